// Round 10
// baseline (59.312 us; speedup 1.0000x reference)
//
#include <hip/hip_runtime.h>
#include <hip/hip_bf16.h>

typedef __bf16 bf16x8 __attribute__((ext_vector_type(8)));
typedef _Float16 f16x8 __attribute__((ext_vector_type(8)));
typedef _Float16 f16x2 __attribute__((ext_vector_type(2)));
typedef float f32x4 __attribute__((ext_vector_type(4)));

#define B_DIM 16
#define L_DIM 1024
#define H_DIM 4
#define HC 128
#define TI 16
#define WPITCH 136   // bf16 elems; 272B rows, 16B-aligned

// ---------------------------------------------------------------------------
// Kernel 1: adjacency -> packed bitmask (proven R7 pattern).
// ---------------------------------------------------------------------------
__global__ __launch_bounds__(256) void mask_pack_kernel(
    const int* __restrict__ adj, unsigned* __restrict__ mask_g)
{
  const int t = threadIdx.x;
  const int wv = t >> 6, lane = t & 63;
  const int row0 = blockIdx.x * 8 + wv * 2;
  const int* base = adj + (size_t)row0 * L_DIM;

  int4 av[8];
#pragma unroll
  for (int c = 0; c < 4; ++c) {
    av[c]     = *reinterpret_cast<const int4*>(base + c * 256 + lane * 4);
    av[c + 4] = *reinterpret_cast<const int4*>(base + 1024 + c * 256 + lane * 4);
  }

#pragma unroll
  for (int r = 0; r < 2; ++r) {
    const int row = row0 + r;
    const int i = row & (L_DIM - 1);
#pragma unroll
    for (int c = 0; c < 4; ++c) {
      const int4 u = av[r * 4 + c];
      unsigned b4 = (unsigned)u.x | ((unsigned)u.y << 1) |
                    ((unsigned)u.z << 2) | ((unsigned)u.w << 3);
      unsigned p;
      p = __shfl_xor(b4, 1);
      unsigned b8  = (lane & 1) ? (p | (b4 << 4))   : (b4 | (p << 4));
      p = __shfl_xor(b8, 2);
      unsigned b16 = (lane & 2) ? (p | (b8 << 8))   : (b8 | (p << 8));
      p = __shfl_xor(b16, 4);
      unsigned b32 = (lane & 4) ? (p | (b16 << 16)) : (b16 | (p << 16));
      const int widx = c * 8 + (lane >> 3);
      if ((i >> 5) == widx) b32 |= (1u << (i & 31));
      if ((lane & 7) == 0) mask_g[(size_t)row * 32 + widx] = b32;
    }
  }
}

// ---------------------------------------------------------------------------
// Kernel 2: projection via MFMA (proven). bf16 hi/lo compensated core,
// fp16 outputs, x16 pre-scale for fp16 range.
// ---------------------------------------------------------------------------
__global__ __launch_bounds__(128) void proj_kernel(
    const float* __restrict__ x, const float* __restrict__ W,
    const float* __restrict__ bias, const float* __restrict__ att_src,
    const float* __restrict__ att_dst, _Float16* __restrict__ xpT,
    _Float16* __restrict__ E1h, _Float16* __restrict__ E2h,
    float* __restrict__ Rr)
{
  __shared__ __align__(16) __bf16 Wlds[128 * WPITCH];
  __shared__ __align__(16) __bf16 xh[32 * WPITCH];
  __shared__ __align__(16) __bf16 xl[32 * WPITCH];
  const int t = threadIdx.x;
  const int w = t >> 6;
  const int lane = t & 63;
  const int r0 = blockIdx.x * 32;

#pragma unroll
  for (int p = 0; p < 16; ++p) {
    const int idx = p * 1024 + t * 8;
    const int n = idx >> 7, k = idx & 127;
    const f32x4 a = *reinterpret_cast<const f32x4*>(W + idx);
    const f32x4 b = *reinterpret_cast<const f32x4*>(W + idx + 4);
    bf16x8 v;
#pragma unroll
    for (int e = 0; e < 4; ++e) { v[e] = (__bf16)a[e]; v[e + 4] = (__bf16)b[e]; }
    *reinterpret_cast<bf16x8*>(&Wlds[n * WPITCH + k]) = v;
  }
#pragma unroll
  for (int p = 0; p < 4; ++p) {
    const int idx = p * 1024 + t * 8;
    const int r = idx >> 7, k = idx & 127;
    const float* xp_ = x + (size_t)(r0 + r) * 128 + k;
    const f32x4 a = *reinterpret_cast<const f32x4*>(xp_);
    const f32x4 b = *reinterpret_cast<const f32x4*>(xp_ + 4);
    bf16x8 vh, vl;
#pragma unroll
    for (int e = 0; e < 4; ++e) {
      const float fa = a[e], fb = b[e];
      vh[e] = (__bf16)fa;          vh[e + 4] = (__bf16)fb;
      vl[e] = (__bf16)(fa - (float)vh[e]);
      vl[e + 4] = (__bf16)(fb - (float)vh[e + 4]);
    }
    *reinterpret_cast<bf16x8*>(&xh[r * WPITCH + k]) = vh;
    *reinterpret_cast<bf16x8*>(&xl[r * WPITCH + k]) = vl;
  }
  __syncthreads();

  const int rr = lane & 15;
  const int g8 = (lane >> 4) * 8;
  f32x4 acc[8] = {};
#pragma unroll
  for (int kk = 0; kk < 4; ++kk) {
    const int ko = kk * 32 + g8;
    const bf16x8 bh = *reinterpret_cast<const bf16x8*>(&xh[(w * 16 + rr) * WPITCH + ko]);
    const bf16x8 bl = *reinterpret_cast<const bf16x8*>(&xl[(w * 16 + rr) * WPITCH + ko]);
#pragma unroll
    for (int nc = 0; nc < 8; ++nc) {
      const bf16x8 af = *reinterpret_cast<const bf16x8*>(&Wlds[(nc * 16 + rr) * WPITCH + ko]);
      acc[nc] = __builtin_amdgcn_mfma_f32_16x16x32_bf16(af, bh, acc[nc], 0, 0, 0);
      acc[nc] = __builtin_amdgcn_mfma_f32_16x16x32_bf16(af, bl, acc[nc], 0, 0, 0);
    }
  }

  const int q4 = (lane >> 4) * 4;
  const int grow = r0 + w * 16 + rr;
  const int bb = grow >> 10;
  const int lg = grow & 1023;
  float asum[4] = {0.f, 0.f, 0.f, 0.f};
  float adsum[4] = {0.f, 0.f, 0.f, 0.f};
#pragma unroll
  for (int nc = 0; nc < 8; ++nc) {
    const int n0 = nc * 16 + q4;
    const f32x4 bv = *reinterpret_cast<const f32x4*>(bias + n0);
    const f32x4 sv = *reinterpret_cast<const f32x4*>(att_src + n0);
    const f32x4 dv = *reinterpret_cast<const f32x4*>(att_dst + n0);
    const int h = nc >> 1;
#pragma unroll
    for (int reg = 0; reg < 4; ++reg) {
      const float v = acc[nc][reg] + bv[reg];
      const int n = n0 + reg;
      xpT[((size_t)bb * 128 + n) * 1024 + lg] = (_Float16)v;
      asum[h]  = fmaf(v, sv[reg], asum[h]);
      adsum[h] = fmaf(v, dv[reg], adsum[h]);
    }
  }
#pragma unroll
  for (int h = 0; h < 4; ++h) {
    asum[h]  += __shfl_xor(asum[h], 16);
    asum[h]  += __shfl_xor(asum[h], 32);
    adsum[h] += __shfl_xor(adsum[h], 16);
    adsum[h] += __shfl_xor(adsum[h], 32);
  }
  if ((lane >> 4) == 0) {
#pragma unroll
    for (int h = 0; h < 4; ++h) {
      const size_t o = ((size_t)bb * 4 + h) * 1024 + lg;
      E1h[o] = (_Float16)(16.0f * __expf(asum[h]));
      E2h[o] = (_Float16)__expf(0.2f * asum[h]);
      Rr[o]  = 16.0f * __expf(-0.8f * adsum[h]);
    }
  }
}

// ---------------------------------------------------------------------------
// Kernel 3 (flash attn, j-split 8-wave blocks):
//   512 thr = 8 waves; wave = (head h = wv>>1, j-half jh = wv&1).
//   Each wave: 16 iters of K=32 over j in [jh*512, jh*512+512).
//   P' = max(16e1, e2*16R) & VALU-expanded mask; 3 f16 MFMAs/iter;
//   2-deep xpT ring (VGPR<=64 for 8 waves/SIMD); e-reads pipelined.
//   Combine: jh=1 waves dump acc/accS to padded LDS; jh=0 adds, normalizes,
//   stores. 4 blocks/CU x 8 waves = 32 waves/CU target.
// ---------------------------------------------------------------------------
__global__ __launch_bounds__(512, 8) void gat_attn_kernel(
    const unsigned* __restrict__ mask_g, const _Float16* __restrict__ xpT,
    const _Float16* __restrict__ E1h, const _Float16* __restrict__ E2h,
    const float* __restrict__ Rr, float* __restrict__ out)
{
  __shared__ __align__(16) unsigned e1u[H_DIM][512];      // 8 KB
  __shared__ __align__(16) unsigned e2u[H_DIM][512];      // 8 KB
  __shared__ __align__(8) unsigned char msk_b[TI][176];   // 2.75 KB
  __shared__ float comb[H_DIM][64][13];                   // 13.3 KB, stride-13: conflict-free

  const int wg  = blockIdx.x;
  const int xcd = wg & 7;
  const int idx = wg >> 3;
  const int b   = xcd * 2 + (idx & 1);
  const int i0  = (idx >> 1) * TI;

  const int t = threadIdx.x;
  const int wv = t >> 6;        // 0..7
  const int lane = t & 63;
  const int h  = wv >> 1;       // head
  const int jh = wv & 1;        // j-half

  // ---- staging: msk (first 256 threads), e1/e2 (all 512, one uint4 each) ----
  if (t < 256) {
    const int r = t >> 4, sg = t & 15;
    const uint2 m = *reinterpret_cast<const uint2*>(
        mask_g + ((size_t)b * L_DIM + i0 + r) * 32 + sg * 2);
    *reinterpret_cast<uint2*>(&msk_b[r][sg * 8]) = m;
  }
  {
    const int sh = t >> 7;          // head for staging
    const int off = (t & 127) * 8;  // element offset within head slice
    const _Float16* p1 = E1h + ((size_t)(b * H_DIM + sh)) * L_DIM + off;
    const _Float16* p2 = E2h + ((size_t)(b * H_DIM + sh)) * L_DIM + off;
    *reinterpret_cast<uint4*>(&e1u[sh][off >> 1]) = *reinterpret_cast<const uint4*>(p1);
    *reinterpret_cast<uint4*>(&e2u[sh][off >> 1]) = *reinterpret_cast<const uint4*>(p2);
  }
  __syncthreads();

  const int ln15 = lane & 15;
  const int kh = lane >> 4;
  const int jb = kh * 8;
  const int base = jh * 512;
  const float Rrow = Rr[((size_t)(b * H_DIM + h)) * L_DIM + i0 + ln15];
  const _Float16 rh = (_Float16)Rrow;
  const f16x2 R2 = {rh, rh};
  const _Float16* xb0 = xpT + ((size_t)(b * 128 + h * 32 + ln15)) * 1024 + base;
  const _Float16* xb1 = xb0 + 16 * 1024;

  f32x4 acc0 = {0.f, 0.f, 0.f, 0.f};
  f32x4 acc1 = {0.f, 0.f, 0.f, 0.f};
  f32x4 accS = {0.f, 0.f, 0.f, 0.f};
  f16x8 ones16;
#pragma unroll
  for (int e = 0; e < 8; ++e) ones16[e] = (_Float16)1.0f;

  // 2-deep xpT ring (16 VGPRs)
  uint4 pf0[2], pf1[2];
#pragma unroll
  for (int s = 0; s < 2; ++s) {
    pf0[s] = *reinterpret_cast<const uint4*>(xb0 + s * 32 + jb);
    pf1[s] = *reinterpret_cast<const uint4*>(xb1 + s * 32 + jb);
  }

  // mask-group prefetch (uint4 = 4 words = 128 j) + e-read pipeline
  uint4 mw_pf = *reinterpret_cast<const uint4*>(&msk_b[ln15][jh * 64]);
  uint4 mwc = mw_pf;
  uint4 u1c = *reinterpret_cast<const uint4*>(&e1u[h][(base + jb) >> 1]);
  uint4 u2c = *reinterpret_cast<const uint4*>(&e2u[h][(base + jb) >> 1]);

#pragma unroll 4
  for (int kr = 0; kr < 512; kr += 32) {
    const int k0 = base + kr;
    const int tm = (kr >> 5) & 3;
    if (tm == 0) {
      mwc = mw_pf;
      if (kr < 384)
        mw_pf = *reinterpret_cast<const uint4*>(
            &msk_b[ln15][jh * 64 + (kr >> 7) * 16 + 16]);
    }
    const unsigned word = (tm == 0) ? mwc.x : (tm == 1) ? mwc.y
                        : (tm == 2) ? mwc.z : mwc.w;
    const unsigned mb = (word >> (kh * 8)) & 0xffu;

    // next-iter e-reads (wrap keeps address in-bounds; value unused at end)
    const int kn = (((k0 + 32) & 1023) + jb) >> 1;
    const uint4 u1n = *reinterpret_cast<const uint4*>(&e1u[h][kn]);
    const uint4 u2n = *reinterpret_cast<const uint4*>(&e2u[h][kn]);

    const int sl = (kr >> 5) & 1;
    const uint4 bb0 = pf0[sl];
    const uint4 bb1 = pf1[sl];
    pf0[sl] = *reinterpret_cast<const uint4*>(xb0 + kr + 64 + jb);  // over-read lands in ws
    pf1[sl] = *reinterpret_cast<const uint4*>(xb1 + kr + 64 + jb);

    const unsigned uu1[4] = {u1c.x, u1c.y, u1c.z, u1c.w};
    const unsigned uu2[4] = {u2c.x, u2c.y, u2c.z, u2c.w};
    unsigned rr4[4];
#pragma unroll
    for (int q = 0; q < 4; ++q) {
      f16x2 a, ee;
      __builtin_memcpy(&a,  &uu1[q], 4);
      __builtin_memcpy(&ee, &uu2[q], 4);
      const f16x2 pr = ee * R2;                            // v_pk_mul_f16
      const f16x2 mx = __builtin_elementwise_max(a, pr);   // v_pk_max_f16
      unsigned mu;
      __builtin_memcpy(&mu, &mx, 4);
      const unsigned mlo = (mb & (1u << (2 * q)))     ? 0xFFFFu : 0u;
      const unsigned mhi = (mb & (1u << (2 * q + 1))) ? 0xFFFF0000u : 0u;
      rr4[q] = mu & (mlo | mhi);
    }
    const uint4 afu = {rr4[0], rr4[1], rr4[2], rr4[3]};
    f16x8 af, b0h, b1h;
    __builtin_memcpy(&af,  &afu, 16);
    __builtin_memcpy(&b0h, &bb0, 16);
    __builtin_memcpy(&b1h, &bb1, 16);
    acc0 = __builtin_amdgcn_mfma_f32_16x16x32_f16(af, b0h, acc0, 0, 0, 0);
    acc1 = __builtin_amdgcn_mfma_f32_16x16x32_f16(af, b1h, acc1, 0, 0, 0);
    accS = __builtin_amdgcn_mfma_f32_16x16x32_f16(af, ones16, accS, 0, 0, 0);
    u1c = u1n; u2c = u2n;
  }

  // ---- combine: jh=1 dumps partials; jh=0 adds, normalizes, stores ----
  if (jh == 1) {
    float* cp = &comb[h][lane][0];
#pragma unroll
    for (int e = 0; e < 4; ++e) {
      cp[e]     = acc0[e];
      cp[4 + e] = acc1[e];
      cp[8 + e] = accS[e];
    }
  }
  __syncthreads();
  if (jh == 0) {
    const float* cp = &comb[h][lane][0];
#pragma unroll
    for (int reg = 0; reg < 4; ++reg) {
      const float s = accS[reg] + cp[8 + reg];
      const float rs = 1.0f / s;
      float* op = out + ((size_t)(b * L_DIM + i0 + kh * 4 + reg)) * HC + h * 32;
      op[ln15]      = (acc0[reg] + cp[reg])     * rs;
      op[16 + ln15] = (acc1[reg] + cp[4 + reg]) * rs;
    }
  }
}

extern "C" void kernel_launch(void* const* d_in, const int* in_sizes, int n_in,
                              void* d_out, int out_size, void* d_ws, size_t ws_size,
                              hipStream_t stream) {
  (void)in_sizes; (void)n_in; (void)out_size; (void)ws_size;
  const float* x        = (const float*)d_in[0];
  const int*   adj      = (const int*)d_in[1];
  const float* W        = (const float*)d_in[2];
  const float* bias     = (const float*)d_in[3];
  const float* att_src  = (const float*)d_in[4];
  const float* att_dst  = (const float*)d_in[5];
  float* out = (float*)d_out;

  char* ws = (char*)d_ws;
  _Float16* xpT    = (_Float16*)ws;                                    // 4 MiB
  _Float16* E1h    = (_Float16*)(ws + (size_t)4 * 1024 * 1024);        // 128 KiB
  _Float16* E2h    = (_Float16*)(ws + (size_t)4 * 1024 * 1024 + 131072);
  float*    Rr     = (float*)(ws + (size_t)4 * 1024 * 1024 + 262144);  // 256 KiB
  unsigned* mask_g = (unsigned*)(ws + (size_t)4 * 1024 * 1024 + 524288); // 2 MiB

  hipLaunchKernelGGL(mask_pack_kernel, dim3(B_DIM * L_DIM / 8), dim3(256), 0, stream,
                     adj, mask_g);
  hipLaunchKernelGGL(proj_kernel, dim3(B_DIM * L_DIM / 32), dim3(128), 0, stream,
                     x, W, bias, att_src, att_dst, xpT, E1h, E2h, Rr);
  hipLaunchKernelGGL(gat_attn_kernel, dim3(B_DIM * L_DIM / TI), dim3(512), 0, stream,
                     mask_g, xpT, E1h, E2h, Rr, out);
}

// Round 11
// 43.045 us; speedup vs baseline: 1.3779x; 1.3779x over previous
//
#include <hip/hip_runtime.h>
#include <hip/hip_bf16.h>

typedef __bf16 bf16x8 __attribute__((ext_vector_type(8)));
typedef _Float16 f16x8 __attribute__((ext_vector_type(8)));
typedef _Float16 f16x2 __attribute__((ext_vector_type(2)));
typedef float f32x4 __attribute__((ext_vector_type(4)));

#define B_DIM 16
#define L_DIM 1024
#define H_DIM 4
#define HC 128
#define TI 32
#define WPITCH 136   // bf16 elems; 272B rows, 16B-aligned

// ---------------------------------------------------------------------------
// Kernel 1: adjacency -> packed bitmask (proven R7 pattern).
// ---------------------------------------------------------------------------
__global__ __launch_bounds__(256) void mask_pack_kernel(
    const int* __restrict__ adj, unsigned* __restrict__ mask_g)
{
  const int t = threadIdx.x;
  const int wv = t >> 6, lane = t & 63;
  const int row0 = blockIdx.x * 8 + wv * 2;
  const int* base = adj + (size_t)row0 * L_DIM;

  int4 av[8];
#pragma unroll
  for (int c = 0; c < 4; ++c) {
    av[c]     = *reinterpret_cast<const int4*>(base + c * 256 + lane * 4);
    av[c + 4] = *reinterpret_cast<const int4*>(base + 1024 + c * 256 + lane * 4);
  }

#pragma unroll
  for (int r = 0; r < 2; ++r) {
    const int row = row0 + r;
    const int i = row & (L_DIM - 1);
#pragma unroll
    for (int c = 0; c < 4; ++c) {
      const int4 u = av[r * 4 + c];
      unsigned b4 = (unsigned)u.x | ((unsigned)u.y << 1) |
                    ((unsigned)u.z << 2) | ((unsigned)u.w << 3);
      unsigned p;
      p = __shfl_xor(b4, 1);
      unsigned b8  = (lane & 1) ? (p | (b4 << 4))   : (b4 | (p << 4));
      p = __shfl_xor(b8, 2);
      unsigned b16 = (lane & 2) ? (p | (b8 << 8))   : (b8 | (p << 8));
      p = __shfl_xor(b16, 4);
      unsigned b32 = (lane & 4) ? (p | (b16 << 16)) : (b16 | (p << 16));
      const int widx = c * 8 + (lane >> 3);
      if ((i >> 5) == widx) b32 |= (1u << (i & 31));
      if ((lane & 7) == 0) mask_g[(size_t)row * 32 + widx] = b32;
    }
  }
}

// ---------------------------------------------------------------------------
// Kernel 2: projection via MFMA (proven). bf16 hi/lo compensated core,
// fp16 outputs, x16 pre-scale for fp16 range.
// ---------------------------------------------------------------------------
__global__ __launch_bounds__(128) void proj_kernel(
    const float* __restrict__ x, const float* __restrict__ W,
    const float* __restrict__ bias, const float* __restrict__ att_src,
    const float* __restrict__ att_dst, _Float16* __restrict__ xpT,
    _Float16* __restrict__ E1h, _Float16* __restrict__ E2h,
    float* __restrict__ Rr)
{
  __shared__ __align__(16) __bf16 Wlds[128 * WPITCH];
  __shared__ __align__(16) __bf16 xh[32 * WPITCH];
  __shared__ __align__(16) __bf16 xl[32 * WPITCH];
  const int t = threadIdx.x;
  const int w = t >> 6;
  const int lane = t & 63;
  const int r0 = blockIdx.x * 32;

#pragma unroll
  for (int p = 0; p < 16; ++p) {
    const int idx = p * 1024 + t * 8;
    const int n = idx >> 7, k = idx & 127;
    const f32x4 a = *reinterpret_cast<const f32x4*>(W + idx);
    const f32x4 b = *reinterpret_cast<const f32x4*>(W + idx + 4);
    bf16x8 v;
#pragma unroll
    for (int e = 0; e < 4; ++e) { v[e] = (__bf16)a[e]; v[e + 4] = (__bf16)b[e]; }
    *reinterpret_cast<bf16x8*>(&Wlds[n * WPITCH + k]) = v;
  }
#pragma unroll
  for (int p = 0; p < 4; ++p) {
    const int idx = p * 1024 + t * 8;
    const int r = idx >> 7, k = idx & 127;
    const float* xp_ = x + (size_t)(r0 + r) * 128 + k;
    const f32x4 a = *reinterpret_cast<const f32x4*>(xp_);
    const f32x4 b = *reinterpret_cast<const f32x4*>(xp_ + 4);
    bf16x8 vh, vl;
#pragma unroll
    for (int e = 0; e < 4; ++e) {
      const float fa = a[e], fb = b[e];
      vh[e] = (__bf16)fa;          vh[e + 4] = (__bf16)fb;
      vl[e] = (__bf16)(fa - (float)vh[e]);
      vl[e + 4] = (__bf16)(fb - (float)vh[e + 4]);
    }
    *reinterpret_cast<bf16x8*>(&xh[r * WPITCH + k]) = vh;
    *reinterpret_cast<bf16x8*>(&xl[r * WPITCH + k]) = vl;
  }
  __syncthreads();

  const int rr = lane & 15;
  const int g8 = (lane >> 4) * 8;
  f32x4 acc[8] = {};
#pragma unroll
  for (int kk = 0; kk < 4; ++kk) {
    const int ko = kk * 32 + g8;
    const bf16x8 bh = *reinterpret_cast<const bf16x8*>(&xh[(w * 16 + rr) * WPITCH + ko]);
    const bf16x8 bl = *reinterpret_cast<const bf16x8*>(&xl[(w * 16 + rr) * WPITCH + ko]);
#pragma unroll
    for (int nc = 0; nc < 8; ++nc) {
      const bf16x8 af = *reinterpret_cast<const bf16x8*>(&Wlds[(nc * 16 + rr) * WPITCH + ko]);
      acc[nc] = __builtin_amdgcn_mfma_f32_16x16x32_bf16(af, bh, acc[nc], 0, 0, 0);
      acc[nc] = __builtin_amdgcn_mfma_f32_16x16x32_bf16(af, bl, acc[nc], 0, 0, 0);
    }
  }

  const int q4 = (lane >> 4) * 4;
  const int grow = r0 + w * 16 + rr;
  const int bb = grow >> 10;
  const int lg = grow & 1023;
  float asum[4] = {0.f, 0.f, 0.f, 0.f};
  float adsum[4] = {0.f, 0.f, 0.f, 0.f};
#pragma unroll
  for (int nc = 0; nc < 8; ++nc) {
    const int n0 = nc * 16 + q4;
    const f32x4 bv = *reinterpret_cast<const f32x4*>(bias + n0);
    const f32x4 sv = *reinterpret_cast<const f32x4*>(att_src + n0);
    const f32x4 dv = *reinterpret_cast<const f32x4*>(att_dst + n0);
    const int h = nc >> 1;
#pragma unroll
    for (int reg = 0; reg < 4; ++reg) {
      const float v = acc[nc][reg] + bv[reg];
      const int n = n0 + reg;
      xpT[((size_t)bb * 128 + n) * 1024 + lg] = (_Float16)v;
      asum[h]  = fmaf(v, sv[reg], asum[h]);
      adsum[h] = fmaf(v, dv[reg], adsum[h]);
    }
  }
#pragma unroll
  for (int h = 0; h < 4; ++h) {
    asum[h]  += __shfl_xor(asum[h], 16);
    asum[h]  += __shfl_xor(asum[h], 32);
    adsum[h] += __shfl_xor(adsum[h], 16);
    adsum[h] += __shfl_xor(adsum[h], 32);
  }
  if ((lane >> 4) == 0) {
#pragma unroll
    for (int h = 0; h < 4; ++h) {
      const size_t o = ((size_t)bb * 4 + h) * 1024 + lg;
      E1h[o] = (_Float16)(16.0f * __expf(asum[h]));
      E2h[o] = (_Float16)__expf(0.2f * asum[h]);
      Rr[o]  = 16.0f * __expf(-0.8f * adsum[h]);
    }
  }
}

// ---------------------------------------------------------------------------
// Kernel 3 (flash attn, TI=32, 2 row-groups per wave):
//   512 thr = 8 waves; wave = (head h = wv>>1, j-half jh = wv&1).
//   Each wave: 16 iters of K=32 over its 512-j half, computing TWO 16-row
//   A-fragments against the SAME xpT/e1/e2 stream (loads amortized 2x,
//   L2 traffic halved vs R10). 6 f16 MFMAs/iter. launch_bounds(512,4):
//   128 regs/thread so rings+masks+6 accs live in registers (R10's 64-reg
//   budget forced AGPR shuttling). Combine via padded LDS.
// ---------------------------------------------------------------------------
__global__ __launch_bounds__(512, 4) void gat_attn_kernel(
    const unsigned* __restrict__ mask_g, const _Float16* __restrict__ xpT,
    const _Float16* __restrict__ E1h, const _Float16* __restrict__ E2h,
    const float* __restrict__ Rr, float* __restrict__ out)
{
  __shared__ __align__(16) unsigned e1u[H_DIM][512];      // 8 KB
  __shared__ __align__(16) unsigned e2u[H_DIM][512];      // 8 KB
  __shared__ __align__(8) unsigned char msk_b[TI][176];   // 5.5 KB
  __shared__ float comb[H_DIM][2][64][13];                // 26.6 KB

  const int wg  = blockIdx.x;
  const int xcd = wg & 7;
  const int idx = wg >> 3;
  const int b   = xcd * 2 + (idx & 1);
  const int i0  = (idx >> 1) * TI;

  const int t = threadIdx.x;
  const int wv = t >> 6;        // 0..7
  const int lane = t & 63;
  const int h  = wv >> 1;       // head
  const int jh = wv & 1;        // j-half

  // ---- staging: msk (512 thr, one uint2 each), e1/e2 (one uint4 each) ----
  {
    const int r = t >> 4, sg = t & 15;
    const uint2 m = *reinterpret_cast<const uint2*>(
        mask_g + ((size_t)b * L_DIM + i0 + r) * 32 + sg * 2);
    *reinterpret_cast<uint2*>(&msk_b[r][sg * 8]) = m;
  }
  {
    const int sh = t >> 7;          // head for staging
    const int off = (t & 127) * 8;  // element offset within head slice
    const _Float16* p1 = E1h + ((size_t)(b * H_DIM + sh)) * L_DIM + off;
    const _Float16* p2 = E2h + ((size_t)(b * H_DIM + sh)) * L_DIM + off;
    *reinterpret_cast<uint4*>(&e1u[sh][off >> 1]) = *reinterpret_cast<const uint4*>(p1);
    *reinterpret_cast<uint4*>(&e2u[sh][off >> 1]) = *reinterpret_cast<const uint4*>(p2);
  }
  __syncthreads();

  const int ln15 = lane & 15;
  const int kh = lane >> 4;
  const int jb = kh * 8;
  const int base = jh * 512;
  // two row-groups: rows i0 + g*16 + ln15
  const float* RrB = Rr + ((size_t)(b * H_DIM + h)) * L_DIM + i0 + ln15;
  const _Float16 rh0 = (_Float16)RrB[0];
  const _Float16 rh1 = (_Float16)RrB[16];
  const f16x2 R2g0 = {rh0, rh0};
  const f16x2 R2g1 = {rh1, rh1};
  const _Float16* xb0 = xpT + ((size_t)(b * 128 + h * 32 + ln15)) * 1024 + base;
  const _Float16* xb1 = xb0 + 16 * 1024;

  f32x4 g0acc0 = {}, g0acc1 = {}, g0accS = {};
  f32x4 g1acc0 = {}, g1acc1 = {}, g1accS = {};
  f16x8 ones16;
#pragma unroll
  for (int e = 0; e < 8; ++e) ones16[e] = (_Float16)1.0f;

  // 2-deep xpT ring
  uint4 pf0[2], pf1[2];
#pragma unroll
  for (int s = 0; s < 2; ++s) {
    pf0[s] = *reinterpret_cast<const uint4*>(xb0 + s * 32 + jb);
    pf1[s] = *reinterpret_cast<const uint4*>(xb1 + s * 32 + jb);
  }

  // mask-word streaming per group (uint4 = 128 j), e-read 1-iter pipeline
  uint4 mw_pf0 = *reinterpret_cast<const uint4*>(&msk_b[ln15][jh * 64]);
  uint4 mw_pf1 = *reinterpret_cast<const uint4*>(&msk_b[16 + ln15][jh * 64]);
  uint4 mwc0 = mw_pf0, mwc1 = mw_pf1;
  uint4 u1c = *reinterpret_cast<const uint4*>(&e1u[h][(base + jb) >> 1]);
  uint4 u2c = *reinterpret_cast<const uint4*>(&e2u[h][(base + jb) >> 1]);

#pragma unroll 4
  for (int kr = 0; kr < 512; kr += 32) {
    const int k0 = base + kr;
    const int tm = (kr >> 5) & 3;
    if (tm == 0) {
      mwc0 = mw_pf0;
      mwc1 = mw_pf1;
      if (kr < 384) {
        mw_pf0 = *reinterpret_cast<const uint4*>(
            &msk_b[ln15][jh * 64 + (kr >> 7) * 16 + 16]);
        mw_pf1 = *reinterpret_cast<const uint4*>(
            &msk_b[16 + ln15][jh * 64 + (kr >> 7) * 16 + 16]);
      }
    }
    const unsigned word0 = (tm == 0) ? mwc0.x : (tm == 1) ? mwc0.y
                         : (tm == 2) ? mwc0.z : mwc0.w;
    const unsigned word1 = (tm == 0) ? mwc1.x : (tm == 1) ? mwc1.y
                         : (tm == 2) ? mwc1.z : mwc1.w;
    const unsigned mb0 = (word0 >> (kh * 8)) & 0xffu;
    const unsigned mb1 = (word1 >> (kh * 8)) & 0xffu;

    // next-iter e-reads (wrap keeps address in-bounds; value unused at end)
    const int kn = (((k0 + 32) & 1023) + jb) >> 1;
    const uint4 u1n = *reinterpret_cast<const uint4*>(&e1u[h][kn]);
    const uint4 u2n = *reinterpret_cast<const uint4*>(&e2u[h][kn]);

    const int sl = (kr >> 5) & 1;
    const uint4 bb0 = pf0[sl];
    const uint4 bb1 = pf1[sl];
    pf0[sl] = *reinterpret_cast<const uint4*>(xb0 + kr + 64 + jb);  // over-read lands in ws
    pf1[sl] = *reinterpret_cast<const uint4*>(xb1 + kr + 64 + jb);

    const unsigned uu1[4] = {u1c.x, u1c.y, u1c.z, u1c.w};
    const unsigned uu2[4] = {u2c.x, u2c.y, u2c.z, u2c.w};
    unsigned r0g[4], r1g[4];
#pragma unroll
    for (int q = 0; q < 4; ++q) {
      f16x2 a, ee;
      __builtin_memcpy(&a,  &uu1[q], 4);
      __builtin_memcpy(&ee, &uu2[q], 4);
      const unsigned mlo0 = (mb0 & (1u << (2 * q)))     ? 0xFFFFu : 0u;
      const unsigned mhi0 = (mb0 & (1u << (2 * q + 1))) ? 0xFFFF0000u : 0u;
      const unsigned mlo1 = (mb1 & (1u << (2 * q)))     ? 0xFFFFu : 0u;
      const unsigned mhi1 = (mb1 & (1u << (2 * q + 1))) ? 0xFFFF0000u : 0u;
      const f16x2 pr0 = ee * R2g0;                          // v_pk_mul_f16
      const f16x2 mx0 = __builtin_elementwise_max(a, pr0);  // v_pk_max_f16
      const f16x2 pr1 = ee * R2g1;
      const f16x2 mx1 = __builtin_elementwise_max(a, pr1);
      unsigned mu0, mu1;
      __builtin_memcpy(&mu0, &mx0, 4);
      __builtin_memcpy(&mu1, &mx1, 4);
      r0g[q] = mu0 & (mlo0 | mhi0);
      r1g[q] = mu1 & (mlo1 | mhi1);
    }
    const uint4 af0u = {r0g[0], r0g[1], r0g[2], r0g[3]};
    const uint4 af1u = {r1g[0], r1g[1], r1g[2], r1g[3]};
    f16x8 af0, af1, b0h, b1h;
    __builtin_memcpy(&af0, &af0u, 16);
    __builtin_memcpy(&af1, &af1u, 16);
    __builtin_memcpy(&b0h, &bb0, 16);
    __builtin_memcpy(&b1h, &bb1, 16);
    g0acc0 = __builtin_amdgcn_mfma_f32_16x16x32_f16(af0, b0h, g0acc0, 0, 0, 0);
    g0acc1 = __builtin_amdgcn_mfma_f32_16x16x32_f16(af0, b1h, g0acc1, 0, 0, 0);
    g0accS = __builtin_amdgcn_mfma_f32_16x16x32_f16(af0, ones16, g0accS, 0, 0, 0);
    g1acc0 = __builtin_amdgcn_mfma_f32_16x16x32_f16(af1, b0h, g1acc0, 0, 0, 0);
    g1acc1 = __builtin_amdgcn_mfma_f32_16x16x32_f16(af1, b1h, g1acc1, 0, 0, 0);
    g1accS = __builtin_amdgcn_mfma_f32_16x16x32_f16(af1, ones16, g1accS, 0, 0, 0);
    u1c = u1n; u2c = u2n;
  }

  // ---- combine: jh=1 dumps partials; jh=0 adds, normalizes, stores ----
  if (jh == 1) {
#pragma unroll
    for (int g = 0; g < 2; ++g) {
      float* cp = &comb[h][g][lane][0];
      const f32x4 a0 = g ? g1acc0 : g0acc0;
      const f32x4 a1 = g ? g1acc1 : g0acc1;
      const f32x4 aS = g ? g1accS : g0accS;
#pragma unroll
      for (int e = 0; e < 4; ++e) {
        cp[e]     = a0[e];
        cp[4 + e] = a1[e];
        cp[8 + e] = aS[e];
      }
    }
  }
  __syncthreads();
  if (jh == 0) {
#pragma unroll
    for (int g = 0; g < 2; ++g) {
      const float* cp = &comb[h][g][lane][0];
      const f32x4 a0 = g ? g1acc0 : g0acc0;
      const f32x4 a1 = g ? g1acc1 : g0acc1;
      const f32x4 aS = g ? g1accS : g0accS;
#pragma unroll
      for (int reg = 0; reg < 4; ++reg) {
        const float s = aS[reg] + cp[8 + reg];
        const float rs = 1.0f / s;
        float* op = out + ((size_t)(b * L_DIM + i0 + g * 16 + kh * 4 + reg)) * HC + h * 32;
        op[ln15]      = (a0[reg] + cp[reg])     * rs;
        op[16 + ln15] = (a1[reg] + cp[4 + reg]) * rs;
      }
    }
  }
}

extern "C" void kernel_launch(void* const* d_in, const int* in_sizes, int n_in,
                              void* d_out, int out_size, void* d_ws, size_t ws_size,
                              hipStream_t stream) {
  (void)in_sizes; (void)n_in; (void)out_size; (void)ws_size;
  const float* x        = (const float*)d_in[0];
  const int*   adj      = (const int*)d_in[1];
  const float* W        = (const float*)d_in[2];
  const float* bias     = (const float*)d_in[3];
  const float* att_src  = (const float*)d_in[4];
  const float* att_dst  = (const float*)d_in[5];
  float* out = (float*)d_out;

  char* ws = (char*)d_ws;
  _Float16* xpT    = (_Float16*)ws;                                    // 4 MiB
  _Float16* E1h    = (_Float16*)(ws + (size_t)4 * 1024 * 1024);        // 128 KiB
  _Float16* E2h    = (_Float16*)(ws + (size_t)4 * 1024 * 1024 + 131072);
  float*    Rr     = (float*)(ws + (size_t)4 * 1024 * 1024 + 262144);  // 256 KiB
  unsigned* mask_g = (unsigned*)(ws + (size_t)4 * 1024 * 1024 + 524288); // 2 MiB

  hipLaunchKernelGGL(mask_pack_kernel, dim3(B_DIM * L_DIM / 8), dim3(256), 0, stream,
                     adj, mask_g);
  hipLaunchKernelGGL(proj_kernel, dim3(B_DIM * L_DIM / 32), dim3(128), 0, stream,
                     x, W, bias, att_src, att_dst, xpT, E1h, E2h, Rr);
  hipLaunchKernelGGL(gat_attn_kernel, dim3(B_DIM * L_DIM / TI), dim3(512), 0, stream,
                     mask_g, xpT, E1h, E2h, Rr, out);
}

// Round 12
// 41.329 us; speedup vs baseline: 1.4351x; 1.0415x over previous
//
#include <hip/hip_runtime.h>
#include <hip/hip_bf16.h>

typedef __bf16 bf16x8 __attribute__((ext_vector_type(8)));
typedef _Float16 f16x8 __attribute__((ext_vector_type(8)));
typedef _Float16 f16x2 __attribute__((ext_vector_type(2)));
typedef float f32x4 __attribute__((ext_vector_type(4)));

#define B_DIM 16
#define L_DIM 1024
#define H_DIM 4
#define HC 128
#define TI 64
#define WPITCH 136   // bf16 elems; 272B rows, 16B-aligned

// ---------------------------------------------------------------------------
// Kernel 1: adjacency -> packed bitmask (proven R7 pattern).
// ---------------------------------------------------------------------------
__global__ __launch_bounds__(256) void mask_pack_kernel(
    const int* __restrict__ adj, unsigned* __restrict__ mask_g)
{
  const int t = threadIdx.x;
  const int wv = t >> 6, lane = t & 63;
  const int row0 = blockIdx.x * 8 + wv * 2;
  const int* base = adj + (size_t)row0 * L_DIM;

  int4 av[8];
#pragma unroll
  for (int c = 0; c < 4; ++c) {
    av[c]     = *reinterpret_cast<const int4*>(base + c * 256 + lane * 4);
    av[c + 4] = *reinterpret_cast<const int4*>(base + 1024 + c * 256 + lane * 4);
  }

#pragma unroll
  for (int r = 0; r < 2; ++r) {
    const int row = row0 + r;
    const int i = row & (L_DIM - 1);
#pragma unroll
    for (int c = 0; c < 4; ++c) {
      const int4 u = av[r * 4 + c];
      unsigned b4 = (unsigned)u.x | ((unsigned)u.y << 1) |
                    ((unsigned)u.z << 2) | ((unsigned)u.w << 3);
      unsigned p;
      p = __shfl_xor(b4, 1);
      unsigned b8  = (lane & 1) ? (p | (b4 << 4))   : (b4 | (p << 4));
      p = __shfl_xor(b8, 2);
      unsigned b16 = (lane & 2) ? (p | (b8 << 8))   : (b8 | (p << 8));
      p = __shfl_xor(b16, 4);
      unsigned b32 = (lane & 4) ? (p | (b16 << 16)) : (b16 | (p << 16));
      const int widx = c * 8 + (lane >> 3);
      if ((i >> 5) == widx) b32 |= (1u << (i & 31));
      if ((lane & 7) == 0) mask_g[(size_t)row * 32 + widx] = b32;
    }
  }
}

// ---------------------------------------------------------------------------
// Kernel 2: projection via MFMA (proven). bf16 hi/lo compensated core,
// fp16 outputs, x16 pre-scale for fp16 range.
// ---------------------------------------------------------------------------
__global__ __launch_bounds__(128) void proj_kernel(
    const float* __restrict__ x, const float* __restrict__ W,
    const float* __restrict__ bias, const float* __restrict__ att_src,
    const float* __restrict__ att_dst, _Float16* __restrict__ xpT,
    _Float16* __restrict__ E1h, _Float16* __restrict__ E2h,
    float* __restrict__ Rr)
{
  __shared__ __align__(16) __bf16 Wlds[128 * WPITCH];
  __shared__ __align__(16) __bf16 xh[32 * WPITCH];
  __shared__ __align__(16) __bf16 xl[32 * WPITCH];
  const int t = threadIdx.x;
  const int w = t >> 6;
  const int lane = t & 63;
  const int r0 = blockIdx.x * 32;

#pragma unroll
  for (int p = 0; p < 16; ++p) {
    const int idx = p * 1024 + t * 8;
    const int n = idx >> 7, k = idx & 127;
    const f32x4 a = *reinterpret_cast<const f32x4*>(W + idx);
    const f32x4 b = *reinterpret_cast<const f32x4*>(W + idx + 4);
    bf16x8 v;
#pragma unroll
    for (int e = 0; e < 4; ++e) { v[e] = (__bf16)a[e]; v[e + 4] = (__bf16)b[e]; }
    *reinterpret_cast<bf16x8*>(&Wlds[n * WPITCH + k]) = v;
  }
#pragma unroll
  for (int p = 0; p < 4; ++p) {
    const int idx = p * 1024 + t * 8;
    const int r = idx >> 7, k = idx & 127;
    const float* xp_ = x + (size_t)(r0 + r) * 128 + k;
    const f32x4 a = *reinterpret_cast<const f32x4*>(xp_);
    const f32x4 b = *reinterpret_cast<const f32x4*>(xp_ + 4);
    bf16x8 vh, vl;
#pragma unroll
    for (int e = 0; e < 4; ++e) {
      const float fa = a[e], fb = b[e];
      vh[e] = (__bf16)fa;          vh[e + 4] = (__bf16)fb;
      vl[e] = (__bf16)(fa - (float)vh[e]);
      vl[e + 4] = (__bf16)(fb - (float)vh[e + 4]);
    }
    *reinterpret_cast<bf16x8*>(&xh[r * WPITCH + k]) = vh;
    *reinterpret_cast<bf16x8*>(&xl[r * WPITCH + k]) = vl;
  }
  __syncthreads();

  const int rr = lane & 15;
  const int g8 = (lane >> 4) * 8;
  f32x4 acc[8] = {};
#pragma unroll
  for (int kk = 0; kk < 4; ++kk) {
    const int ko = kk * 32 + g8;
    const bf16x8 bh = *reinterpret_cast<const bf16x8*>(&xh[(w * 16 + rr) * WPITCH + ko]);
    const bf16x8 bl = *reinterpret_cast<const bf16x8*>(&xl[(w * 16 + rr) * WPITCH + ko]);
#pragma unroll
    for (int nc = 0; nc < 8; ++nc) {
      const bf16x8 af = *reinterpret_cast<const bf16x8*>(&Wlds[(nc * 16 + rr) * WPITCH + ko]);
      acc[nc] = __builtin_amdgcn_mfma_f32_16x16x32_bf16(af, bh, acc[nc], 0, 0, 0);
      acc[nc] = __builtin_amdgcn_mfma_f32_16x16x32_bf16(af, bl, acc[nc], 0, 0, 0);
    }
  }

  const int q4 = (lane >> 4) * 4;
  const int grow = r0 + w * 16 + rr;
  const int bb = grow >> 10;
  const int lg = grow & 1023;
  float asum[4] = {0.f, 0.f, 0.f, 0.f};
  float adsum[4] = {0.f, 0.f, 0.f, 0.f};
#pragma unroll
  for (int nc = 0; nc < 8; ++nc) {
    const int n0 = nc * 16 + q4;
    const f32x4 bv = *reinterpret_cast<const f32x4*>(bias + n0);
    const f32x4 sv = *reinterpret_cast<const f32x4*>(att_src + n0);
    const f32x4 dv = *reinterpret_cast<const f32x4*>(att_dst + n0);
    const int h = nc >> 1;
#pragma unroll
    for (int reg = 0; reg < 4; ++reg) {
      const float v = acc[nc][reg] + bv[reg];
      const int n = n0 + reg;
      xpT[((size_t)bb * 128 + n) * 1024 + lg] = (_Float16)v;
      asum[h]  = fmaf(v, sv[reg], asum[h]);
      adsum[h] = fmaf(v, dv[reg], adsum[h]);
    }
  }
#pragma unroll
  for (int h = 0; h < 4; ++h) {
    asum[h]  += __shfl_xor(asum[h], 16);
    asum[h]  += __shfl_xor(asum[h], 32);
    adsum[h] += __shfl_xor(adsum[h], 16);
    adsum[h] += __shfl_xor(adsum[h], 32);
  }
  if ((lane >> 4) == 0) {
#pragma unroll
    for (int h = 0; h < 4; ++h) {
      const size_t o = ((size_t)bb * 4 + h) * 1024 + lg;
      E1h[o] = (_Float16)(16.0f * __expf(asum[h]));
      E2h[o] = (_Float16)__expf(0.2f * asum[h]);
      Rr[o]  = 16.0f * __expf(-0.8f * adsum[h]);
    }
  }
}

// ---------------------------------------------------------------------------
// Kernel 3 (flash attn, TI=64, FOUR row-groups per wave):
//   512 thr = 8 waves; wave = (head h = wv>>1, j-half jh = wv&1).
//   16 iters of K=32 over the wave's 512-j half; each iter builds FOUR
//   16-row A-fragments (rows i0+g*16+ln15) from ONE e1/e2/xpT stream
//   (loads amortized 4x vs R9; L2 traffic halved vs R11). 12 f16 MFMAs/iter
//   (accumulators live in AGPRs; arch-reg state kept ~80 by reading mask
//   words per-iter from LDS instead of register-streaming them).
//   Combine buffer OVERLAYS e/msk LDS (used only after a post-loop barrier).
// ---------------------------------------------------------------------------
__global__ __launch_bounds__(512, 4) void gat_attn_kernel(
    const unsigned* __restrict__ mask_g, const _Float16* __restrict__ xpT,
    const _Float16* __restrict__ E1h, const _Float16* __restrict__ E2h,
    const float* __restrict__ Rr, float* __restrict__ out)
{
  // 52 KB raw smem; phase 1: e1u[4][512] | e2u[4][512] | msk[64][176]
  //                  phase 2 (after barrier): comb[4][4][64][13] floats
  __shared__ __align__(16) char smem[53248];
  unsigned* e1u = reinterpret_cast<unsigned*>(smem);                  // [h][512]
  unsigned* e2u = reinterpret_cast<unsigned*>(smem + 8192);           // [h][512]
  unsigned char* msk = reinterpret_cast<unsigned char*>(smem + 16384); // [64][176]
  float* comb = reinterpret_cast<float*>(smem);                       // [h][g][64][13]

  const int wg  = blockIdx.x;     // 256 blocks
  const int xcd = wg & 7;
  const int idx = wg >> 3;
  const int b   = xcd * 2 + (idx & 1);
  const int i0  = (idx >> 1) * TI;

  const int t = threadIdx.x;
  const int wv = t >> 6;        // 0..7
  const int lane = t & 63;
  const int h  = wv >> 1;       // head
  const int jh = wv & 1;        // j-half

  // ---- staging: msk rows (512 thr -> 64 rows x 8B... 2 passes of uint2),
  //      e1/e2 (one uint4 per thread) ----
  {
    const int r = t >> 3, sg = t & 7;        // 64 rows x 8 segs of 16B
    const uint4 m = *reinterpret_cast<const uint4*>(
        mask_g + ((size_t)b * L_DIM + i0 + r) * 32 + sg * 4);
    *reinterpret_cast<uint4*>(&msk[r * 176 + sg * 16]) = m;
  }
  {
    const int sh = t >> 7;          // head for staging
    const int off = (t & 127) * 8;  // element offset within head slice
    const _Float16* p1 = E1h + ((size_t)(b * H_DIM + sh)) * L_DIM + off;
    const _Float16* p2 = E2h + ((size_t)(b * H_DIM + sh)) * L_DIM + off;
    *reinterpret_cast<uint4*>(&e1u[sh * 512 + (off >> 1)]) = *reinterpret_cast<const uint4*>(p1);
    *reinterpret_cast<uint4*>(&e2u[sh * 512 + (off >> 1)]) = *reinterpret_cast<const uint4*>(p2);
  }
  __syncthreads();

  const int ln15 = lane & 15;
  const int kh = lane >> 4;
  const int jb = kh * 8;
  const int base = jh * 512;
  // four row-groups: rows i0 + g*16 + ln15
  const float* RrB = Rr + ((size_t)(b * H_DIM + h)) * L_DIM + i0 + ln15;
  f16x2 R2g[4];
#pragma unroll
  for (int g = 0; g < 4; ++g) {
    const _Float16 rh = (_Float16)RrB[g * 16];
    R2g[g][0] = rh; R2g[g][1] = rh;
  }
  const _Float16* xb0 = xpT + ((size_t)(b * 128 + h * 32 + ln15)) * 1024 + base;
  const _Float16* xb1 = xb0 + 16 * 1024;

  f32x4 acc0[4] = {}, acc1[4] = {}, accS[4] = {};
  f16x8 ones16;
#pragma unroll
  for (int e = 0; e < 8; ++e) ones16[e] = (_Float16)1.0f;

  // 2-deep xpT ring
  uint4 pf0[2], pf1[2];
#pragma unroll
  for (int s = 0; s < 2; ++s) {
    pf0[s] = *reinterpret_cast<const uint4*>(xb0 + s * 32 + jb);
    pf1[s] = *reinterpret_cast<const uint4*>(xb1 + s * 32 + jb);
  }
  // e-read 1-iter pipeline
  uint4 u1c = *reinterpret_cast<const uint4*>(&e1u[h * 512 + ((base + jb) >> 1)]);
  uint4 u2c = *reinterpret_cast<const uint4*>(&e2u[h * 512 + ((base + jb) >> 1)]);

#pragma unroll 4
  for (int kr = 0; kr < 512; kr += 32) {
    const int k0 = base + kr;
    // per-group mask words from LDS (rows differ per lane: 2-way bank = free)
    const int wb = jh * 64 + ((kr >> 5) << 2);   // byte offset of word in row
    unsigned mb[4];
#pragma unroll
    for (int g = 0; g < 4; ++g) {
      const unsigned w32 = *reinterpret_cast<const unsigned*>(
          &msk[(g * 16 + ln15) * 176 + wb]);
      mb[g] = (w32 >> (kh * 8)) & 0xffu;
    }

    // next-iter e-reads (wrap keeps address in-bounds; value unused at end)
    const int kn = (((k0 + 32) & 1023) + jb) >> 1;
    const uint4 u1n = *reinterpret_cast<const uint4*>(&e1u[h * 512 + kn]);
    const uint4 u2n = *reinterpret_cast<const uint4*>(&e2u[h * 512 + kn]);

    const int sl = (kr >> 5) & 1;
    const uint4 bb0 = pf0[sl];
    const uint4 bb1 = pf1[sl];
    pf0[sl] = *reinterpret_cast<const uint4*>(xb0 + kr + 64 + jb);  // over-read lands in ws
    pf1[sl] = *reinterpret_cast<const uint4*>(xb1 + kr + 64 + jb);

    const unsigned uu1[4] = {u1c.x, u1c.y, u1c.z, u1c.w};
    const unsigned uu2[4] = {u2c.x, u2c.y, u2c.z, u2c.w};
    unsigned rg[4][4];
#pragma unroll
    for (int q = 0; q < 4; ++q) {
      f16x2 a, ee;
      __builtin_memcpy(&a,  &uu1[q], 4);
      __builtin_memcpy(&ee, &uu2[q], 4);
#pragma unroll
      for (int g = 0; g < 4; ++g) {
        const f16x2 pr = ee * R2g[g];                         // v_pk_mul_f16
        const f16x2 mx = __builtin_elementwise_max(a, pr);    // v_pk_max_f16
        unsigned mu;
        __builtin_memcpy(&mu, &mx, 4);
        const unsigned mlo = (mb[g] & (1u << (2 * q)))     ? 0xFFFFu : 0u;
        const unsigned mhi = (mb[g] & (1u << (2 * q + 1))) ? 0xFFFF0000u : 0u;
        rg[g][q] = mu & (mlo | mhi);
      }
    }
    f16x8 b0h, b1h;
    __builtin_memcpy(&b0h, &bb0, 16);
    __builtin_memcpy(&b1h, &bb1, 16);
#pragma unroll
    for (int g = 0; g < 4; ++g) {
      const uint4 afu = {rg[g][0], rg[g][1], rg[g][2], rg[g][3]};
      f16x8 af;
      __builtin_memcpy(&af, &afu, 16);
      acc0[g] = __builtin_amdgcn_mfma_f32_16x16x32_f16(af, b0h, acc0[g], 0, 0, 0);
      acc1[g] = __builtin_amdgcn_mfma_f32_16x16x32_f16(af, b1h, acc1[g], 0, 0, 0);
      accS[g] = __builtin_amdgcn_mfma_f32_16x16x32_f16(af, ones16, accS[g], 0, 0, 0);
    }
    u1c = u1n; u2c = u2n;
  }

  // ---- combine (comb OVERLAYS e/msk: barrier before any write) ----
  __syncthreads();
  if (jh == 1) {
#pragma unroll
    for (int g = 0; g < 4; ++g) {
      float* cp = &comb[((h * 4 + g) * 64 + lane) * 13];
#pragma unroll
      for (int e = 0; e < 4; ++e) {
        cp[e]     = acc0[g][e];
        cp[4 + e] = acc1[g][e];
        cp[8 + e] = accS[g][e];
      }
    }
  }
  __syncthreads();
  if (jh == 0) {
#pragma unroll
    for (int g = 0; g < 4; ++g) {
      const float* cp = &comb[((h * 4 + g) * 64 + lane) * 13];
#pragma unroll
      for (int reg = 0; reg < 4; ++reg) {
        const float s = accS[g][reg] + cp[8 + reg];
        const float rs = 1.0f / s;
        float* op = out + ((size_t)(b * L_DIM + i0 + g * 16 + kh * 4 + reg)) * HC + h * 32;
        op[ln15]      = (acc0[g][reg] + cp[reg])     * rs;
        op[16 + ln15] = (acc1[g][reg] + cp[4 + reg]) * rs;
      }
    }
  }
}

extern "C" void kernel_launch(void* const* d_in, const int* in_sizes, int n_in,
                              void* d_out, int out_size, void* d_ws, size_t ws_size,
                              hipStream_t stream) {
  (void)in_sizes; (void)n_in; (void)out_size; (void)ws_size;
  const float* x        = (const float*)d_in[0];
  const int*   adj      = (const int*)d_in[1];
  const float* W        = (const float*)d_in[2];
  const float* bias     = (const float*)d_in[3];
  const float* att_src  = (const float*)d_in[4];
  const float* att_dst  = (const float*)d_in[5];
  float* out = (float*)d_out;

  char* ws = (char*)d_ws;
  _Float16* xpT    = (_Float16*)ws;                                    // 4 MiB
  _Float16* E1h    = (_Float16*)(ws + (size_t)4 * 1024 * 1024);        // 128 KiB
  _Float16* E2h    = (_Float16*)(ws + (size_t)4 * 1024 * 1024 + 131072);
  float*    Rr     = (float*)(ws + (size_t)4 * 1024 * 1024 + 262144);  // 256 KiB
  unsigned* mask_g = (unsigned*)(ws + (size_t)4 * 1024 * 1024 + 524288); // 2 MiB

  hipLaunchKernelGGL(mask_pack_kernel, dim3(B_DIM * L_DIM / 8), dim3(256), 0, stream,
                     adj, mask_g);
  hipLaunchKernelGGL(proj_kernel, dim3(B_DIM * L_DIM / 32), dim3(128), 0, stream,
                     x, W, bias, att_src, att_dst, xpT, E1h, E2h, Rr);
  hipLaunchKernelGGL(gat_attn_kernel, dim3(B_DIM * L_DIM / TI), dim3(512), 0, stream,
                     mask_g, xpT, E1h, E2h, Rr, out);
}